// Round 1
// 101.399 us; speedup vs baseline: 1.0114x; 1.0114x over previous
//
#include <hip/hip_runtime.h>

// ChannelPolyLayer: out[b,o,x,y] = sum_c coeffs[b,o,c] * prod_v img[b,v,x,y]^powers[c,v]
// B=16, NUM_VARS=3, NUM_OUT=3, H=W=512, NUM_COEFFS=20 (deg<=3 monomials in 3 vars).
//
// R3: same fused structure as R2 (LDS-canonicalized coeffs -> SGPRs via
// readfirstlane, straight-line monomial eval), but 16 pixels/thread
// (4 float4 groups) instead of 4, and all 12 global loads issued BEFORE the
// coeff-staging prologue. Rationale: at 4 px/thread the 120-instr prologue
// was ~30% of the wave's instruction stream and only 3 loads were in flight
// at wave start; amortizing 4x + load-first ordering targets the ~1.7 us gap
// between the measured ~17.7 us kernel portion and the 16 us HBM floor.
// dur_us is dominated by harness re-poison fills (~2 x 42.4 us) we can't touch.

#define PLANE (512 * 512)
#define NC 20
#define NV 3
#define NO 3
#define NB 16
#define G  4   // float4 groups per thread => 16 pixels/thread

// Canonical monomial order for exponent triple (a,b,c), a+b+c<=3:
//  0:1 | 1:x 2:y 3:z | 4:x2 5:xy 6:xz 7:y2 8:yz 9:z2
// 10:x3 11:x2y 12:x2z 13:xy2 14:xyz 15:xz2 16:y3 17:y2z 18:yz2 19:z3
__device__ __forceinline__ int canon_idx(int a, int b, int c) {
    int d = a + b + c;
    if (d == 0) return 0;
    if (d == 1) return a ? 1 : (b ? 2 : 3);
    if (d == 2) {
        if (a == 2) return 4;
        if (a == 1) return (b == 1) ? 5 : 6;
        return (b == 2) ? 7 : ((b == 1) ? 8 : 9);
    }
    // d == 3
    if (a == 3) return 10;
    if (a == 2) return (b == 1) ? 11 : 12;
    if (a == 1) return (b == 2) ? 13 : ((b == 1) ? 14 : 15);
    return (b == 3) ? 16 : ((b == 2) ? 17 : ((b == 1) ? 18 : 19));
}

__device__ __forceinline__ void eval_pixel(float x, float y, float z,
                                           const float (&cc)[NO * NC],
                                           float& o0, float& o1, float& o2) {
    float x2 = x * x, y2 = y * y, z2 = z * z;
    float xy = x * y, xz = x * z, yz = y * z;
    float m[NC];
    m[0] = 1.0f;    m[1] = x;       m[2] = y;       m[3] = z;
    m[4] = x2;      m[5] = xy;      m[6] = xz;      m[7] = y2;
    m[8] = yz;      m[9] = z2;      m[10] = x2 * x; m[11] = x2 * y;
    m[12] = x2 * z; m[13] = x * y2; m[14] = xy * z; m[15] = x * z2;
    m[16] = y2 * y; m[17] = y2 * z; m[18] = y * z2; m[19] = z2 * z;
    float a0 = 0.0f, a1 = 0.0f, a2 = 0.0f;
#pragma unroll
    for (int i = 0; i < NC; i++) {
        // cc[] values are SGPRs (readfirstlane) -> v_fma_f32 s,v,v single op.
        a0 = fmaf(cc[i],          m[i], a0);
        a1 = fmaf(cc[NC + i],     m[i], a1);
        a2 = fmaf(cc[2 * NC + i], m[i], a2);
    }
    o0 = a0; o1 = a1; o2 = a2;
}

__global__ __launch_bounds__(256) void channel_poly_kernel(
        const float* __restrict__ img,
        const float* __restrict__ coeffs,
        const float* __restrict__ powers,
        float* __restrict__ out) {
    const int b   = blockIdx.y;
    const int tid = threadIdx.x;

    // --- Issue ALL global loads first: 12 x global_load_dwordx4 in flight ---
    // Consecutive threads hit consecutive float4 within each group (coalesced);
    // groups stride by blockDim so the block covers a contiguous 4 KiB*G span.
    const int t0 = blockIdx.x * (256 * G) + tid;  // float4 index base
    const float* ibase = img + (size_t)b * NV * PLANE;
    const float4* Xp = (const float4*)ibase;
    const float4* Yp = (const float4*)(ibase + PLANE);
    const float4* Zp = (const float4*)(ibase + 2 * PLANE);

    float4 X[G], Y[G], Z[G];
#pragma unroll
    for (int g = 0; g < G; g++) {
        X[g] = Xp[t0 + g * 256];
        Y[g] = Yp[t0 + g * 256];
        Z[g] = Zp[t0 + g * 256];
    }

    // --- Stage this batch's 60 coeffs into LDS in canonical monomial order ---
    // (hides under the VMEM latency of the loads above)
    __shared__ float cstage[NO * NC];
    if (tid < NO * NC) {
        int c  = tid % NC;             // coeff index within output channel
        int o  = tid / NC;             // output channel
        int ea = (int)powers[c * NV + 0];
        int eb = (int)powers[c * NV + 1];
        int ec = (int)powers[c * NV + 2];
        cstage[o * NC + canon_idx(ea, eb, ec)] = coeffs[b * NO * NC + tid];
    }
    __syncthreads();

    // Wave-uniform LDS values -> SGPRs so the FMA loop reads scalar operands.
    float cc[NO * NC];
#pragma unroll
    for (int i = 0; i < NO * NC; i++) {
        cc[i] = __int_as_float(__builtin_amdgcn_readfirstlane(__float_as_int(cstage[i])));
    }

    // --- Evaluate + store, one float4 group at a time (bounded live range) ---
    float* obase = out + (size_t)b * NO * PLANE;
    float4* O0p = (float4*)obase;
    float4* O1p = (float4*)(obase + PLANE);
    float4* O2p = (float4*)(obase + 2 * PLANE);

#pragma unroll
    for (int g = 0; g < G; g++) {
        float4 O0, O1, O2;
        eval_pixel(X[g].x, Y[g].x, Z[g].x, cc, O0.x, O1.x, O2.x);
        eval_pixel(X[g].y, Y[g].y, Z[g].y, cc, O0.y, O1.y, O2.y);
        eval_pixel(X[g].z, Y[g].z, Z[g].z, cc, O0.z, O1.z, O2.z);
        eval_pixel(X[g].w, Y[g].w, Z[g].w, cc, O0.w, O1.w, O2.w);
        O0p[t0 + g * 256] = O0;
        O1p[t0 + g * 256] = O1;
        O2p[t0 + g * 256] = O2;
    }
}

extern "C" void kernel_launch(void* const* d_in, const int* in_sizes, int n_in,
                              void* d_out, int out_size, void* d_ws, size_t ws_size,
                              hipStream_t stream) {
    const float* img    = (const float*)d_in[0];
    const float* coeffs = (const float*)d_in[1];
    const float* powers = (const float*)d_in[2];
    float* out = (float*)d_out;
    (void)d_ws; (void)ws_size;

    // 16 pixels/thread: grid = (512*512 / 16 / 256, 16) = (64, 16).
    dim3 grid(PLANE / 4 / 256 / G, NB);
    channel_poly_kernel<<<grid, dim3(256), 0, stream>>>(img, coeffs, powers, out);
}